// Round 2
// 391.692 us; speedup vs baseline: 1.0523x; 1.0523x over previous
//
#include <hip/hip_runtime.h>
#include <math.h>

// Problem constants (fixed by setup_inputs)
#define TOKENS 50176   // B*T*H*W = 2*8*56*56
#define NWIN   512     // total windows = B * 256
#define C_DIM  256

typedef __attribute__((ext_vector_type(8))) short short8;
typedef __attribute__((ext_vector_type(4))) float f32x4;

// float -> bf16 with round-to-nearest-even
__device__ __forceinline__ unsigned short f2bf(float f) {
    unsigned int u = __builtin_bit_cast(unsigned int, f);
    u += 0x7fffu + ((u >> 16) & 1);
    return (unsigned short)(u >> 16);
}

// async global->LDS, 16B per lane (global_load_lds_dwordx4)
__device__ __forceinline__ void gll16(const void* g, void* l) {
    __builtin_amdgcn_global_load_lds(
        (const __attribute__((address_space(1))) unsigned int*)g,
        (__attribute__((address_space(3))) unsigned int*)l, 16, 0, 0);
}

// Map a window-ordered token index u -> flat (b,t,h,w) index.
// Serves BOTH gather (roll(-)+partition) and scatter (reverse+roll(+)).
__device__ __forceinline__ int win_token_to_flat(int u) {
    int g = u / 98;
    int n = u - g * 98;
    int bb  = g >> 8;
    int rem = g & 255;
    int tb = rem >> 6, hb = (rem >> 3) & 7, wb = rem & 7;
    int dt = n / 49;
    int r2 = n - dt * 49;
    int dh = r2 / 7, dw = r2 - dh * 7;
    int t = tb * 2 + dt, h = hb * 7 + dh, w = wb * 7 + dw;
    int ts = (t + 1) & 7;
    int hs = h + 3; if (hs >= 56) hs -= 56;
    int wsx = w + 3; if (wsx >= 56) wsx -= 56;
    return ((bb * 8 + ts) * 56 + hs) * 56 + wsx;
}

// elementwise fp32 -> bf16 (weights)
__global__ __launch_bounds__(256) void cvt_kernel(
        const float* __restrict__ src, unsigned short* __restrict__ dst, int n) {
    int i = blockIdx.x * 256 + threadIdx.x;
    if (i < n) dst[i] = f2bf(src[i]);
}

// Precompute combined rel-pos bias + shift mask tables:
// bm[cls 8][head 8][row 112][col 112] fp32. cls bits: (tb==3)<<2 | (hb==7)<<1 | (wb==7).
// col >= 98 -> -1e30 (padded K tokens), row >= 98 -> 0 (harmless pad rows).
__global__ __launch_bounds__(256) void bm_kernel(
        const float* __restrict__ rpe, float* __restrict__ bm) {
    int i = blockIdx.x * 256 + threadIdx.x;   // 8*8*112*112 = 802816 exact
    int c  = i % 112;
    int t1 = i / 112;
    int r  = t1 % 112;
    int t2 = t1 / 112;
    int head = t2 & 7;
    int cls  = t2 >> 3;
    float val;
    if (c >= 98) {
        val = -1e30f;
    } else if (r >= 98) {
        val = 0.f;
    } else {
        int dt = r / 49, rr = r - dt * 49, dh = rr / 7, dw = rr - dh * 7;
        int dt2 = c / 49, cc = c - dt2 * 49, dh2 = cc / 7, dw2 = cc - dh2 * 7;
        int rt  = (cls & 4) ? (dt  == 0 ? 1 : 2) : 0;
        int rh  = (cls & 2) ? (dh  <  4 ? 1 : 2) : 0;
        int rw  = (cls & 1) ? (dw  <  4 ? 1 : 2) : 0;
        int rt2 = (cls & 4) ? (dt2 == 0 ? 1 : 2) : 0;
        int rh2 = (cls & 2) ? (dh2 <  4 ? 1 : 2) : 0;
        int rw2 = (cls & 1) ? (dw2 <  4 ? 1 : 2) : 0;
        int reg1 = rt * 9 + rh * 3 + rw, reg2 = rt2 * 9 + rh2 * 3 + rw2;
        int idx = (dt - dt2 + 1) * 169 + (dh - dh2 + 6) * 13 + (dw - dw2 + 6);
        val = rpe[idx * 8 + head] + ((reg1 == reg2) ? 0.f : -100.f);
    }
    bm[i] = val;
}

// LayerNorm over C=256, one wave per token, bf16 output.
// GATHER=true: LN1 + roll + window partition fused (gather).
template<bool GATHER>
__global__ __launch_bounds__(256) void ln_kernel(
        const float* __restrict__ x, const float* __restrict__ w,
        const float* __restrict__ b, unsigned short* __restrict__ out) {
    int token = blockIdx.x * 4 + (threadIdx.x >> 6);
    int lane  = threadIdx.x & 63;
    size_t so = GATHER ? (size_t)win_token_to_flat(token) * C_DIM
                       : (size_t)token * C_DIM;
    const float* src = x + so;
    float v[4];
    float sum = 0.f;
#pragma unroll
    for (int j = 0; j < 4; ++j) { v[j] = src[lane + 64 * j]; sum += v[j]; }
#pragma unroll
    for (int o = 32; o > 0; o >>= 1) sum += __shfl_xor(sum, o, 64);
    float mu = sum * (1.f / 256.f);
    float var = 0.f;
#pragma unroll
    for (int j = 0; j < 4; ++j) { float d = v[j] - mu; var += d * d; }
#pragma unroll
    for (int o = 32; o > 0; o >>= 1) var += __shfl_xor(var, o, 64);
    float rstd = rsqrtf(var * (1.f / 256.f) + 1e-5f);
    unsigned short* dst = out + (size_t)token * C_DIM;
#pragma unroll
    for (int j = 0; j < 4; ++j) {
        int c = lane + 64 * j;
        dst[c] = f2bf((v[j] - mu) * rstd * w[c] + b[c]);
    }
}

// bf16 MFMA GEMM: C(MxN) = A(MxK) @ B(NxK)^T.
// v2 structure: double-buffered LDS (BK=32, 32KB total), 2-phase prefetch
// (next K-tile's global_load_lds issued before current tile's MFMAs; ONE
// barrier per K-step drains it), XCD-bijective block swizzle (all grids
// here are %8==0), and chunk-XOR LDS swizzle (chunk ^= (row>>2)&3 applied
// on the GLOBAL source + matching XOR on the ds_read -> 8-way bank
// conflict becomes free 2-way; gll16 dest stays linear per rule #21).
// EPI: 0 = +bias, *scale on Q cols (col0<256), bf16 store   (qkv)
//      1 = +bias, scatter via map, +res, fp32               (proj)
//      2 = +bias, exact GELU, bf16 store                    (fc1)
//      3 = +bias, +res in place, fp32                       (fc2)
template<int EPI>
__global__ __launch_bounds__(256) void mfma_gemm(
        const unsigned short* __restrict__ A, const unsigned short* __restrict__ B,
        const float* __restrict__ bias, const float* __restrict__ res,
        void* __restrict__ Cout, int M, int N, int K) {
    __shared__ __attribute__((aligned(16))) unsigned short Asm[2][128 * 32];
    __shared__ __attribute__((aligned(16))) unsigned short Bsm[2][128 * 32];
    int tid = threadIdx.x;
    int wave = tid >> 6, lane = tid & 63;

    // XCD-aware bijective swizzle: each XCD gets a contiguous run of the
    // grid -> the 8 (or 2/6) column-tiles sharing one A row-panel land on
    // the SAME XCD's L2 instead of 8 different ones.
    int nwg = gridDim.x * gridDim.y;
    int bid = blockIdx.y * gridDim.x + blockIdx.x;
    int swz = (bid & 7) * (nwg >> 3) + (bid >> 3);
    int bx = swz % gridDim.x, by = swz / gridDim.x;

    int row0 = by * 128, col0 = bx * 128;
    int wr = (wave >> 1) * 64;
    int wc = (wave & 1) * 64;

    f32x4 acc[4][4] = {};

    // staging: thread tid -> LDS linear offset tid*16B = row (tid>>2),
    // chunk (tid&3). Source chunk is XOR-swizzled by (row>>2)&3.
    int sr = tid >> 2;
    int sk = (((tid & 3) ^ ((sr >> 2) & 3)) * 8);
    const unsigned short* Ag0 = A + (size_t)(row0 + sr) * K + sk;
    const unsigned short* Ag1 = A + (size_t)(row0 + 64 + sr) * K + sk;
    const unsigned short* Bg0 = B + (size_t)(col0 + sr) * K + sk;
    const unsigned short* Bg1 = B + (size_t)(col0 + 64 + sr) * K + sk;
    int loff = tid * 8;

    int fm = lane & 15, fq = lane >> 4;
    // fragment read chunk, same XOR: row bits 2-3 within a 16-row strip = fm bits 2-3
    int fks = (fq ^ ((fm >> 2) & 3)) * 8;

    // prologue: stage K-tile 0 into buffer 0
    gll16(Ag0, &Asm[0][loff]);
    gll16(Ag1, &Asm[0][loff + 2048]);
    gll16(Bg0, &Bsm[0][loff]);
    gll16(Bg1, &Bsm[0][loff + 2048]);

    int nk = K >> 5;
    for (int s = 0; s < nk; ++s) {
        int cur = s & 1;
        __syncthreads();   // drains vmcnt: buf[cur] staged; buf[cur^1] reads done
        if (s + 1 < nk) {
            int k0 = (s + 1) << 5;
            gll16(Ag0 + k0, &Asm[cur ^ 1][loff]);
            gll16(Ag1 + k0, &Asm[cur ^ 1][loff + 2048]);
            gll16(Bg0 + k0, &Bsm[cur ^ 1][loff]);
            gll16(Bg1 + k0, &Bsm[cur ^ 1][loff + 2048]);
        }
        short8 af[4], bfr[4];
#pragma unroll
        for (int t4 = 0; t4 < 4; ++t4) {
            af[t4]  = *(const short8*)&Asm[cur][(wr + t4 * 16 + fm) * 32 + fks];
            bfr[t4] = *(const short8*)&Bsm[cur][(wc + t4 * 16 + fm) * 32 + fks];
        }
#pragma unroll
        for (int i = 0; i < 4; ++i)
#pragma unroll
            for (int j = 0; j < 4; ++j)
                acc[i][j] = __builtin_amdgcn_mfma_f32_16x16x32_bf16(
                    af[i], bfr[j], acc[i][j], 0, 0, 0);
    }

    int crow0 = row0 + wr + (lane >> 4) * 4;
    int ccol0 = col0 + wc + (lane & 15);
    float bj[4];
#pragma unroll
    for (int j = 0; j < 4; ++j) bj[j] = bias[ccol0 + j * 16];

    if (EPI == 0) {
        unsigned short* C = (unsigned short*)Cout;
        float mul = (col0 < 256) ? 0.17677669529663687f : 1.f;  // scale Q
#pragma unroll
        for (int i = 0; i < 4; ++i)
#pragma unroll
            for (int v = 0; v < 4; ++v) {
                size_t base = (size_t)(crow0 + i * 16 + v) * N + ccol0;
#pragma unroll
                for (int j = 0; j < 4; ++j)
                    C[base + j * 16] = f2bf((acc[i][j][v] + bj[j]) * mul);
            }
    } else if (EPI == 1) {
        float* C = (float*)Cout;
#pragma unroll
        for (int i = 0; i < 4; ++i)
#pragma unroll
            for (int v = 0; v < 4; ++v) {
                int r = crow0 + i * 16 + v;
                size_t base = (size_t)win_token_to_flat(r) * C_DIM + ccol0;
#pragma unroll
                for (int j = 0; j < 4; ++j)
                    C[base + j * 16] = res[base + j * 16] + acc[i][j][v] + bj[j];
            }
    } else if (EPI == 2) {
        unsigned short* C = (unsigned short*)Cout;
#pragma unroll
        for (int i = 0; i < 4; ++i)
#pragma unroll
            for (int v = 0; v < 4; ++v) {
                size_t base = (size_t)(crow0 + i * 16 + v) * N + ccol0;
#pragma unroll
                for (int j = 0; j < 4; ++j) {
                    float val = acc[i][j][v] + bj[j];
                    C[base + j * 16] =
                        f2bf(0.5f * val * (1.f + erff(val * 0.70710678118654752f)));
                }
            }
    } else {
        float* C = (float*)Cout;
#pragma unroll
        for (int i = 0; i < 4; ++i)
#pragma unroll
            for (int v = 0; v < 4; ++v) {
                size_t base = (size_t)(crow0 + i * 16 + v) * N + ccol0;
#pragma unroll
                for (int j = 0; j < 4; ++j)
                    C[base + j * 16] = res[base + j * 16] + acc[i][j][v] + bj[j];
            }
    }
}

// MFMA windowed attention: one block per (window, head), 4 waves.
// N=98 padded to 112 (7 row-strips of 16). Per strip (owned by one wave):
//   S = Q K^T (7 MFMA, A/B frags direct from global, row-clamped)
//   + bm table, row softmax (16-lane shfl_xor), P -> LDS (C->A layout),
//   O = P V via 8 MFMA against LDS-transposed V, *1/rowsum at store.
// qkv is bf16, Q pre-scaled by 32^-0.5 in the qkv GEMM epilogue.
__global__ __launch_bounds__(256) void attn_mfma_kernel(
        const unsigned short* __restrict__ qkv, const float* __restrict__ bm,
        unsigned short* __restrict__ out) {
    __shared__ __attribute__((aligned(16))) unsigned short Vt[32][136];
    __shared__ __attribute__((aligned(16))) unsigned short Pw[4][16][136];
    int blk = blockIdx.x;
    int g = blk >> 3, head = blk & 7;
    int tid = threadIdx.x, wave = tid >> 6, lane = tid & 63;

    // zero Vt token-pad cols [98,128) (P pad cols are exact 0, need finite V there)
    for (int i = tid; i < 32 * 30; i += 256) {
        int d = i / 30, c = 98 + (i - d * 30);
        Vt[d][c] = 0;
    }
    // stage V_h transposed: Vt[d][token], coalesced global reads
    const unsigned short* vbase = qkv + (size_t)g * 98 * 768 + 512 + head * 32;
    for (int i = tid; i < 98 * 16; i += 256) {
        int n = i >> 4, dp = i & 15;
        unsigned int val = *(const unsigned int*)(vbase + (size_t)n * 768 + dp * 2);
        Vt[dp * 2][n]     = (unsigned short)val;
        Vt[dp * 2 + 1][n] = (unsigned short)(val >> 16);
    }
    // zero per-wave P k-pad cols [112,128) (read by last PV k-step)
    {
        int m = lane >> 2, c = 112 + (lane & 3) * 4;
        *(unsigned long long*)&Pw[wave][m][c] = 0ULL;
    }
    __syncthreads();

    const unsigned short* qbase = qkv + (size_t)g * 98 * 768 + head * 32;
    const unsigned short* kbase = qbase + 256;
    int rem = g & 255;
    int cls = (((rem >> 6) == 3) << 2) | (((((rem >> 3) & 7)) == 7) << 1) | ((rem & 7) == 7);
    const float* bmh = bm + (size_t)(cls * 8 + head) * 112 * 112;

    int fm = lane & 15, fq = lane >> 4;
    int fk = fq * 8;
    unsigned short* obase = out + (size_t)g * 98 * 256 + head * 32;

    for (int s = wave; s < 7; s += 4) {
        int m0 = s * 16;
        int arow = m0 + fm; if (arow > 97) arow = 97;   // clamp pad rows (finite garbage)
        short8 af = *(const short8*)(qbase + (size_t)arow * 768 + fk);
        f32x4 S[7];
        f32x4 z = {0.f, 0.f, 0.f, 0.f};
#pragma unroll
        for (int j = 0; j < 7; ++j) {
            int krow = j * 16 + fm; if (krow > 97) krow = 97;
            short8 kf = *(const short8*)(kbase + (size_t)krow * 768 + fk);
            S[j] = __builtin_amdgcn_mfma_f32_16x16x32_bf16(af, kf, z, 0, 0, 0);
        }
        // + bias/mask table (pad cols get -1e30 -> exp 0)
        const float* bmrow = bmh + (m0 + fq * 4) * 112 + fm;
#pragma unroll
        for (int j = 0; j < 7; ++j)
#pragma unroll
            for (int v = 0; v < 4; ++v)
                S[j][v] += bmrow[v * 112 + j * 16];
        // row softmax: rows live in 16-lane col groups (lane&15), 4 rows/lane (v)
        float inv[4];
#pragma unroll
        for (int v = 0; v < 4; ++v) {
            float m_ = S[0][v];
#pragma unroll
            for (int j = 1; j < 7; ++j) m_ = fmaxf(m_, S[j][v]);
#pragma unroll
            for (int o = 1; o < 16; o <<= 1) m_ = fmaxf(m_, __shfl_xor(m_, o, 64));
            float t = 0.f;
#pragma unroll
            for (int j = 0; j < 7; ++j) { S[j][v] = __expf(S[j][v] - m_); t += S[j][v]; }
#pragma unroll
            for (int o = 1; o < 16; o <<= 1) t += __shfl_xor(t, o, 64);
            inv[v] = 1.f / t;   // applied at output store (PV is linear)
        }
        // P: C-layout -> A-layout via per-wave LDS (same-wave DS ordering, no barrier)
#pragma unroll
        for (int j = 0; j < 7; ++j)
#pragma unroll
            for (int v = 0; v < 4; ++v)
                Pw[wave][fq * 4 + v][j * 16 + fm] = f2bf(S[j][v]);
        // O = P @ V
        f32x4 O0 = {0.f, 0.f, 0.f, 0.f}, O1 = {0.f, 0.f, 0.f, 0.f};
#pragma unroll
        for (int ks = 0; ks < 4; ++ks) {
            short8 pf = *(const short8*)&Pw[wave][fm][ks * 32 + fk];
            short8 v0 = *(const short8*)&Vt[fm][ks * 32 + fk];
            short8 v1 = *(const short8*)&Vt[16 + fm][ks * 32 + fk];
            O0 = __builtin_amdgcn_mfma_f32_16x16x32_bf16(pf, v0, O0, 0, 0, 0);
            O1 = __builtin_amdgcn_mfma_f32_16x16x32_bf16(pf, v1, O1, 0, 0, 0);
        }
#pragma unroll
        for (int v = 0; v < 4; ++v) {
            int row = m0 + fq * 4 + v;
            if (row < 98) {
                obase[(size_t)row * 256 + fm]      = f2bf(O0[v] * inv[v]);
                obase[(size_t)row * 256 + 16 + fm] = f2bf(O1[v] * inv[v]);
            }
        }
    }
}

extern "C" void kernel_launch(void* const* d_in, const int* in_sizes, int n_in,
                              void* d_out, int out_size, void* d_ws, size_t ws_size,
                              hipStream_t stream) {
    const float* x     = (const float*)d_in[0];
    const float* n1w   = (const float*)d_in[1];
    const float* n1b   = (const float*)d_in[2];
    const float* qkvw  = (const float*)d_in[3];
    const float* qkvb  = (const float*)d_in[4];
    const float* projw = (const float*)d_in[5];
    const float* projb = (const float*)d_in[6];
    const float* rpe   = (const float*)d_in[7];
    const float* n2w   = (const float*)d_in[8];
    const float* n2b   = (const float*)d_in[9];
    const float* fc1w  = (const float*)d_in[10];
    const float* fc1b  = (const float*)d_in[11];
    const float* fc2w  = (const float*)d_in[12];
    const float* fc2b  = (const float*)d_in[13];
    float* out = (float*)d_out;

    // workspace layout
    unsigned short* wqkv  = (unsigned short*)d_ws;            // 768*256 bf16
    unsigned short* wproj = wqkv + 768 * 256;                 // 256*256
    unsigned short* wfc1  = wproj + 256 * 256;                // 1024*256
    unsigned short* wfc2  = wfc1 + 1024 * 256;                // 256*1024
    float* bm = (float*)(wfc2 + 256 * 1024);                  // 8*8*112*112 fp32
    unsigned short* actA  = (unsigned short*)(bm + 8 * 8 * 112 * 112); // TOKENS*256 bf16
    unsigned short* attnO = actA + (size_t)TOKENS * 256;      // TOKENS*256 bf16
    unsigned short* qkv_bf = attnO + (size_t)TOKENS * 256;    // TOKENS*768 bf16
    unsigned short* fc1o = qkv_bf;                            // TOKENS*1024 bf16 (aliases dead qkv)

    // 0. bias/mask tables + weight casts
    bm_kernel<<<8 * 8 * 112 * 112 / 256, 256, 0, stream>>>(rpe, bm);
    cvt_kernel<<<(768 * 256 + 255) / 256, 256, 0, stream>>>(qkvw, wqkv, 768 * 256);
    cvt_kernel<<<(256 * 256 + 255) / 256, 256, 0, stream>>>(projw, wproj, 256 * 256);
    cvt_kernel<<<(1024 * 256 + 255) / 256, 256, 0, stream>>>(fc1w, wfc1, 1024 * 256);
    cvt_kernel<<<(256 * 1024 + 255) / 256, 256, 0, stream>>>(fc2w, wfc2, 256 * 1024);

    // 1. LN1 + roll + window partition (gather), bf16 out
    ln_kernel<true><<<TOKENS / 4, 256, 0, stream>>>(x, n1w, n1b, actA);
    // 2. QKV projection -> bf16, Q pre-scaled
    mfma_gemm<0><<<dim3(768 / 128, TOKENS / 128), 256, 0, stream>>>(
        actA, wqkv, qkvb, nullptr, qkv_bf, TOKENS, 768, 256);
    // 3. MFMA windowed attention -> bf16
    attn_mfma_kernel<<<NWIN * 8, 256, 0, stream>>>(qkv_bf, bm, attnO);
    // 4. proj + window reverse + roll back + residual -> d_out (x1, fp32)
    mfma_gemm<1><<<dim3(256 / 128, TOKENS / 128), 256, 0, stream>>>(
        attnO, wproj, projb, x, out, TOKENS, 256, 256);
    // 5. LN2 -> bf16
    ln_kernel<false><<<TOKENS / 4, 256, 0, stream>>>(out, n2w, n2b, actA);
    // 6. FC1 + GELU -> bf16 (aliases dead qkv buffer)
    mfma_gemm<2><<<dim3(1024 / 128, TOKENS / 128), 256, 0, stream>>>(
        actA, wfc1, fc1b, nullptr, fc1o, TOKENS, 1024, 256);
    // 7. FC2 + residual (in place on d_out)
    mfma_gemm<3><<<dim3(256 / 128, TOKENS / 128), 256, 0, stream>>>(
        fc1o, wfc2, fc2b, out, out, TOKENS, 256, 1024);
}